// Round 1
// baseline (431.466 us; speedup 1.0000x reference)
//
#include <hip/hip_runtime.h>
#include <hip/hip_bf16.h>

typedef short bf16x8 __attribute__((ext_vector_type(8)));
typedef float f32x4 __attribute__((ext_vector_type(4)));

#define MFMA16(a,b,c) __builtin_amdgcn_mfma_f32_16x16x32_bf16((a),(b),(c),0,0,0)

__device__ inline unsigned short f32_to_bf16(float f){
  union { float f; unsigned u; } v; v.f = f;
  unsigned u = v.u;
  u += 0x7FFFu + ((u >> 16) & 1u);
  return (unsigned short)(u >> 16);
}

__device__ inline float gelu_tanh(float x){
  float x3 = x*x*x;
  float t = tanhf(0.7978845608028654f*(x + 0.044715f*x3));
  return 0.5f*x*(1.0f+t);
}

__device__ inline void gload16(const void* g, void* l){
  __builtin_amdgcn_global_load_lds(
      (const __attribute__((address_space(1))) void*)g,
      (__attribute__((address_space(3))) void*)l, 16, 0, 0);
}

// ---------------- mask dtype detection -------------------------------------
// int32 0/1 buffer: every 32-bit word is 0 or 1. bool(byte) buffer: words pack
// 4 bytes -> with random 0/1 bytes some word in the first 256 is >1 w.p. ~1.
__global__ void detect_mask_kernel(const unsigned* __restrict__ m, int* __restrict__ flag){
  __shared__ int s;
  if (threadIdx.x == 0) s = 0;
  __syncthreads();
  unsigned w = m[threadIdx.x];
  if (w > 1u) atomicOr(&s, 1);
  __syncthreads();
  if (threadIdx.x == 0) *flag = s;   // 1 => byte/bool storage, 0 => int32
}

// ---------------- weight convert + transpose -------------------------------
// W [K][N] f32 -> WT [N][K] bf16
__global__ __launch_bounds__(256) void transpose_cvt_kernel(
    const float* __restrict__ W, unsigned short* __restrict__ WT, int K, int N){
  __shared__ float tile[32][33];
  int n0 = blockIdx.x*32, k0 = blockIdx.y*32;
  int tx = threadIdx.x & 31, ty = threadIdx.x >> 5;   // ty 0..7
  #pragma unroll
  for (int r=0;r<4;r++)
    tile[ty+8*r][tx] = W[(size_t)(k0+ty+8*r)*N + n0+tx];
  __syncthreads();
  #pragma unroll
  for (int r=0;r<4;r++)
    WT[(size_t)(n0+ty+8*r)*K + k0+tx] = f32_to_bf16(tile[tx][ty+8*r]);
}

__global__ void bias_concat_kernel(const float* __restrict__ bq,
                                   const float* __restrict__ bkv,
                                   float* __restrict__ dst){
  int i = blockIdx.x*256 + threadIdx.x;
  if (i < 3072) dst[i] = (i < 1024) ? bq[i] : bkv[i-1024];
}

// ---------------- layernorm (row = 1024 floats) -----------------------------
__global__ __launch_bounds__(256) void ln_kernel(const float* __restrict__ x,
                                                 unsigned short* __restrict__ xn){
  const int C = 1024;
  size_t row = blockIdx.x;
  float4 v = reinterpret_cast<const float4*>(x + row*C)[threadIdx.x];
  float s = v.x+v.y+v.z+v.w;
  float q = v.x*v.x+v.y*v.y+v.z*v.z+v.w*v.w;
  #pragma unroll
  for (int off=32; off; off>>=1){ s += __shfl_xor(s,off); q += __shfl_xor(q,off); }
  __shared__ float sm[8];
  int wv = threadIdx.x>>6, ln = threadIdx.x&63;
  if (ln==0){ sm[wv]=s; sm[4+wv]=q; }
  __syncthreads();
  float S = sm[0]+sm[1]+sm[2]+sm[3];
  float Q = sm[4]+sm[5]+sm[6]+sm[7];
  float mu  = S*(1.0f/1024.0f);
  float var = Q*(1.0f/1024.0f) - mu*mu;
  float inv = rsqrtf(var + 1e-6f);
  unsigned short o0 = f32_to_bf16((v.x-mu)*inv);
  unsigned short o1 = f32_to_bf16((v.y-mu)*inv);
  unsigned short o2 = f32_to_bf16((v.z-mu)*inv);
  unsigned short o3 = f32_to_bf16((v.w-mu)*inv);
  ushort4 o; o.x=o0; o.y=o1; o.z=o2; o.w=o3;
  reinterpret_cast<ushort4*>(xn + row*C)[threadIdx.x] = o;
}

// ---------------- bf16 MFMA GEMM: C = A[M,K] * BT[N,K]^T (+epilogue) --------
// EPI 0: bias -> bf16 out ; EPI 1: bias+residual -> f32 out ; EPI 2: bias+gelu -> bf16 out
template<int EPI>
__global__ __launch_bounds__(256) void gemm_kernel(
    const unsigned short* __restrict__ A,
    const unsigned short* __restrict__ BT,
    const float* __restrict__ bias,
    const float* __restrict__ resid,
    void* __restrict__ Cout,
    int M, int N, int K)
{
  __shared__ __align__(16) unsigned short lA[2][128*32];
  __shared__ __align__(16) unsigned short lB[2][128*32];
  int tid = threadIdx.x, wave = tid>>6, lane = tid&63;
  int m0 = blockIdx.y*128, n0 = blockIdx.x*128;
  int ln = lane&15, g = lane>>4;

  int srow = wave*16 + (lane>>2);
  int scol = (lane&3)*8;
  const unsigned short* gA0 = A  + (size_t)(m0+srow)*K    + scol;
  const unsigned short* gA1 = A  + (size_t)(m0+64+srow)*K + scol;
  const unsigned short* gB0 = BT + (size_t)(n0+srow)*K    + scol;
  const unsigned short* gB1 = BT + (size_t)(n0+64+srow)*K + scol;
  int lof0 = wave*512;           // wave*16 rows * 32 elems
  int lof1 = 64*32 + wave*512;

  f32x4 acc[4][4] = {};
  int wm = wave>>1, wn = wave&1;

  int nt = K/32;
  gload16(gA0, &lA[0][lof0]);
  gload16(gA1, &lA[0][lof1]);
  gload16(gB0, &lB[0][lof0]);
  gload16(gB1, &lB[0][lof1]);
  __syncthreads();
  int cur = 0;
  for (int t=0; t<nt; ++t){
    if (t+1 < nt){
      int ko = (t+1)*32;
      gload16(gA0+ko, &lA[cur^1][lof0]);
      gload16(gA1+ko, &lA[cur^1][lof1]);
      gload16(gB0+ko, &lB[cur^1][lof0]);
      gload16(gB1+ko, &lB[cur^1][lof1]);
    }
    bf16x8 a[4], b[4];
    const unsigned short* pA = &lA[cur][(wm*64+ln)*32 + g*8];
    const unsigned short* pB = &lB[cur][(wn*64+ln)*32 + g*8];
    #pragma unroll
    for (int i=0;i<4;i++){
      a[i] = *(const bf16x8*)(pA + i*16*32);
      b[i] = *(const bf16x8*)(pB + i*16*32);
    }
    #pragma unroll
    for (int mi=0;mi<4;mi++)
      #pragma unroll
      for (int ni=0;ni<4;ni++)
        acc[mi][ni] = MFMA16(a[mi], b[ni], acc[mi][ni]);
    __syncthreads();
    cur ^= 1;
  }

  #pragma unroll
  for (int mi=0;mi<4;mi++){
    int r0 = m0 + wm*64 + mi*16 + g*4;
    #pragma unroll
    for (int ni=0;ni<4;ni++){
      int c = n0 + wn*64 + ni*16 + ln;
      float bs = bias[c];
      f32x4 cc = acc[mi][ni];
      #pragma unroll
      for (int i=0;i<4;i++){
        int r = r0 + i;
        float v = cc[i] + bs;
        if (EPI == 1){
          v += resid[(size_t)r*N + c];
          ((float*)Cout)[(size_t)r*N + c] = v;
        } else if (EPI == 2){
          ((unsigned short*)Cout)[(size_t)r*N + c] = f32_to_bf16(gelu_tanh(v));
        } else {
          ((unsigned short*)Cout)[(size_t)r*N + c] = f32_to_bf16(v);
        }
      }
    }
  }
}

// ---------------- fused attention ------------------------------------------
// qkv [4096][3072] bf16 (q|k|v each C=1024 wide). One block per (b*16+h, qtile64).
__global__ __launch_bounds__(256) void attn_kernel(
    const unsigned short* __restrict__ qkv,
    const void* __restrict__ mask,
    const int* __restrict__ flagp,
    unsigned short* __restrict__ o)
{
  const int N = 1024, NK = 3072;
  __shared__ __align__(16) unsigned short vT[64][40];        // V^T, padded
  __shared__ __align__(16) unsigned short plds[4][16][32];   // per-wave P transpose
  int bh = blockIdx.x, qt = blockIdx.y;
  int b = bh>>4, h = bh&15;
  int tid = threadIdx.x, wave = tid>>6, lane = tid&63;
  int ln = lane&15, g = lane>>4;
  int fl = *flagp;
  size_t base = (size_t)b*N;
  int q_local = qt*64 + wave*16;

  const unsigned short* qptr = qkv + (base + q_local + ln)*NK + h*64;
  bf16x8 aq0 = *(const bf16x8*)(qptr + g*8);
  bf16x8 aq1 = *(const bf16x8*)(qptr + 32 + g*8);

  f32x4 oacc[4] = {};
  float m_i[4] = {-1e30f,-1e30f,-1e30f,-1e30f};
  float l_i[4] = {0.f,0.f,0.f,0.f};
  const unsigned char* mask8 = (const unsigned char*)mask;
  const int* mask32 = (const int*)mask;

  for (int j0=0; j0<N; j0+=32){
    __syncthreads();
    { // stage V^T for this 32-key tile
      int key = tid>>3, dd = (tid&7)*8;
      const unsigned short* vp = qkv + (base + j0 + key)*NK + 2048 + h*64 + dd;
      bf16x8 vv = *(const bf16x8*)vp;
      #pragma unroll
      for (int e=0;e<8;e++) vT[dd+e][key] = (unsigned short)vv[e];
    }
    __syncthreads();

    f32x4 s0 = {}, s1 = {};
    {
      const unsigned short* kp0 = qkv + (base + j0 + ln)*NK      + 1024 + h*64;
      const unsigned short* kp1 = qkv + (base + j0 + 16 + ln)*NK + 1024 + h*64;
      bf16x8 k00 = *(const bf16x8*)(kp0 + g*8);
      bf16x8 k01 = *(const bf16x8*)(kp0 + 32 + g*8);
      bf16x8 k10 = *(const bf16x8*)(kp1 + g*8);
      bf16x8 k11 = *(const bf16x8*)(kp1 + 32 + g*8);
      s0 = MFMA16(aq0, k00, s0);
      s0 = MFMA16(aq1, k01, s0);
      s1 = MFMA16(aq0, k10, s1);
      s1 = MFMA16(aq1, k11, s1);
    }

    #pragma unroll
    for (int i=0;i<4;i++){
      int qr = q_local + 4*g + i;
      int jc0 = j0 + ln, jc1 = j0 + 16 + ln;
      bool a0 = fl ? (mask8[(size_t)qr*N + jc0] != 0) : (mask32[(size_t)qr*N + jc0] != 0);
      bool a1 = fl ? (mask8[(size_t)qr*N + jc1] != 0) : (mask32[(size_t)qr*N + jc1] != 0);
      float v0 = a0 ? s0[i]*0.125f : -1e30f;
      float v1 = a1 ? s1[i]*0.125f : -1e30f;
      float t = fmaxf(v0, v1);
      t = fmaxf(t, __shfl_xor(t,1));
      t = fmaxf(t, __shfl_xor(t,2));
      t = fmaxf(t, __shfl_xor(t,4));
      t = fmaxf(t, __shfl_xor(t,8));
      float mnew = fmaxf(m_i[i], t);
      float alpha = __expf(m_i[i] - mnew);
      m_i[i] = mnew;
      float e0 = __expf(v0 - mnew);
      float e1 = __expf(v1 - mnew);
      float ls = e0 + e1;
      ls += __shfl_xor(ls,1); ls += __shfl_xor(ls,2);
      ls += __shfl_xor(ls,4); ls += __shfl_xor(ls,8);
      l_i[i] = l_i[i]*alpha + ls;
      #pragma unroll
      for (int nd=0;nd<4;nd++) oacc[nd][i] *= alpha;
      plds[wave][4*g+i][ln]    = f32_to_bf16(e0);
      plds[wave][4*g+i][16+ln] = f32_to_bf16(e1);
    }
    asm volatile("s_waitcnt lgkmcnt(0)" ::: "memory");   // intra-wave LDS W->R
    bf16x8 pf = *(const bf16x8*)&plds[wave][ln][g*8];
    #pragma unroll
    for (int nd=0;nd<4;nd++){
      bf16x8 vf = *(const bf16x8*)&vT[nd*16+ln][g*8];
      oacc[nd] = MFMA16(pf, vf, oacc[nd]);
    }
  }

  #pragma unroll
  for (int nd=0;nd<4;nd++){
    #pragma unroll
    for (int i=0;i<4;i++){
      int qr = q_local + 4*g + i;
      float ov = oacc[nd][i] / l_i[i];
      o[(base+qr)*1024 + h*64 + nd*16 + ln] = f32_to_bf16(ov);
    }
  }
}

// ---------------- host ------------------------------------------------------
extern "C" void kernel_launch(void* const* d_in, const int* in_sizes, int n_in,
                              void* d_out, int out_size, void* d_ws, size_t ws_size,
                              hipStream_t stream)
{
  (void)in_sizes; (void)n_in; (void)out_size; (void)ws_size;
  const float* x   = (const float*)d_in[0];
  const void*  mask= d_in[1];
  const float* wq  = (const float*)d_in[2];
  const float* bq  = (const float*)d_in[3];
  const float* wkv = (const float*)d_in[4];
  const float* bkv = (const float*)d_in[5];
  const float* wo  = (const float*)d_in[6];
  const float* bo  = (const float*)d_in[7];
  const float* w1  = (const float*)d_in[8];
  const float* b1  = (const float*)d_in[9];
  const float* w2  = (const float*)d_in[10];
  const float* b2  = (const float*)d_in[11];
  float* out = (float*)d_out;

  char* ws = (char*)d_ws;
  size_t off = 0;
  auto alloc = [&](size_t bytes){ size_t o = off; off += (bytes + 255) & ~(size_t)255; return o; };
  unsigned short* WqkvT = (unsigned short*)(ws + alloc(3072u*1024u*2));  // [3072][1024]
  unsigned short* WoT   = (unsigned short*)(ws + alloc(1024u*1024u*2));  // [1024][1024]
  unsigned short* W1T   = (unsigned short*)(ws + alloc(4096u*1024u*2));  // [4096][1024]
  unsigned short* W2T   = (unsigned short*)(ws + alloc(1024u*4096u*2));  // [1024][4096]
  float*          BIASQ = (float*)(ws + alloc(3072u*4));
  int*            FLAG  = (int*)(ws + alloc(256));
  unsigned short* XN    = (unsigned short*)(ws + alloc(4096u*1024u*2));  // xn, then attn-out o
  float*          X1    = (float*)(ws + alloc(4096u*1024u*4));           // f32 post-attn residual
  unsigned short* QKV   = (unsigned short*)(ws + alloc(4096u*4096u*2));  // qkv, later h (32MB)

  // weight prep
  transpose_cvt_kernel<<<dim3(32,32),  256, 0, stream>>>(wq,  WqkvT,               1024, 1024);
  transpose_cvt_kernel<<<dim3(64,32),  256, 0, stream>>>(wkv, WqkvT + 1024u*1024u, 1024, 2048);
  transpose_cvt_kernel<<<dim3(32,32),  256, 0, stream>>>(wo,  WoT,                 1024, 1024);
  transpose_cvt_kernel<<<dim3(128,32), 256, 0, stream>>>(w1,  W1T,                 1024, 4096);
  transpose_cvt_kernel<<<dim3(32,128), 256, 0, stream>>>(w2,  W2T,                 4096, 1024);
  bias_concat_kernel<<<12, 256, 0, stream>>>(bq, bkv, BIASQ);
  detect_mask_kernel<<<1, 256, 0, stream>>>((const unsigned*)mask, FLAG);

  // block
  ln_kernel<<<4096, 256, 0, stream>>>(x, XN);
  gemm_kernel<0><<<dim3(24,32), 256, 0, stream>>>(XN, WqkvT, BIASQ, nullptr, QKV, 4096, 3072, 1024);
  attn_kernel<<<dim3(64,16), 256, 0, stream>>>(QKV, mask, FLAG, XN);
  gemm_kernel<1><<<dim3(8,32), 256, 0, stream>>>(XN, WoT, bo, x, X1, 4096, 1024, 1024);
  ln_kernel<<<4096, 256, 0, stream>>>(X1, XN);
  gemm_kernel<2><<<dim3(32,32), 256, 0, stream>>>(XN, W1T, b1, nullptr, QKV, 4096, 4096, 1024);
  gemm_kernel<1><<<dim3(8,32), 256, 0, stream>>>(QKV, W2T, b2, X1, out, 4096, 1024, 4096);
}

// Round 2
// 382.233 us; speedup vs baseline: 1.1288x; 1.1288x over previous
//
#include <hip/hip_runtime.h>
#include <hip/hip_bf16.h>

typedef short bf16x8 __attribute__((ext_vector_type(8)));
typedef float f32x4 __attribute__((ext_vector_type(4)));

#define MFMA16(a,b,c) __builtin_amdgcn_mfma_f32_16x16x32_bf16((a),(b),(c),0,0,0)

__device__ inline unsigned short f32_to_bf16(float f){
  union { float f; unsigned u; } v; v.f = f;
  unsigned u = v.u;
  u += 0x7FFFu + ((u >> 16) & 1u);
  return (unsigned short)(u >> 16);
}

__device__ inline float gelu_tanh(float x){
  float x3 = x*x*x;
  float t = tanhf(0.7978845608028654f*(x + 0.044715f*x3));
  return 0.5f*x*(1.0f+t);
}

__device__ inline void gload16(const void* g, void* l){
  __builtin_amdgcn_global_load_lds(
      (const __attribute__((address_space(1))) void*)g,
      (__attribute__((address_space(3))) void*)l, 16, 0, 0);
}

// ---------------- mask dtype detection -------------------------------------
__global__ void detect_mask_kernel(const unsigned* __restrict__ m, int* __restrict__ flag){
  __shared__ int s;
  if (threadIdx.x == 0) s = 0;
  __syncthreads();
  unsigned w = m[threadIdx.x];
  if (w > 1u) atomicOr(&s, 1);
  __syncthreads();
  if (threadIdx.x == 0) *flag = s;   // 1 => byte/bool storage, 0 => int32
}

// mask -> additive bias, pre-scaled by log2(e), with fixed-max shift M=16 folded in.
// attend: -16*log2e ; masked: -1e30 (exp2 -> 0)
__global__ __launch_bounds__(256) void mask_bias_kernel(
    const void* __restrict__ mask, const int* __restrict__ flag, float* __restrict__ bias){
  int i = blockIdx.x*256 + threadIdx.x;
  bool a = (*flag) ? (((const unsigned char*)mask)[i] != 0)
                   : (((const int*)mask)[i] != 0);
  bias[i] = a ? -23.083120654223414f : -1e30f;
}

// ---------------- weight convert + transpose -------------------------------
// W [K][N] f32 -> WT [N][K] bf16
__global__ __launch_bounds__(256) void transpose_cvt_kernel(
    const float* __restrict__ W, unsigned short* __restrict__ WT, int K, int N){
  __shared__ float tile[32][33];
  int n0 = blockIdx.x*32, k0 = blockIdx.y*32;
  int tx = threadIdx.x & 31, ty = threadIdx.x >> 5;   // ty 0..7
  #pragma unroll
  for (int r=0;r<4;r++)
    tile[ty+8*r][tx] = W[(size_t)(k0+ty+8*r)*N + n0+tx];
  __syncthreads();
  #pragma unroll
  for (int r=0;r<4;r++)
    WT[(size_t)(n0+ty+8*r)*K + k0+tx] = f32_to_bf16(tile[tx][ty+8*r]);
}

// V slice of qkv [4096][3072] -> VT [b][1024 d][1024 n] bf16
__global__ __launch_bounds__(256) void vtrans_kernel(
    const unsigned short* __restrict__ qkv, unsigned short* __restrict__ vt){
  __shared__ unsigned short t[32][33];
  int b = blockIdx.z;
  int n0 = blockIdx.x*32, d0 = blockIdx.y*32;
  int tx = threadIdx.x & 31, ty = threadIdx.x >> 5;
  #pragma unroll
  for (int r=0;r<4;r++)
    t[ty+8*r][tx] = qkv[(size_t)(b*1024 + n0+ty+8*r)*3072 + 2048 + d0+tx];
  __syncthreads();
  #pragma unroll
  for (int r=0;r<4;r++)
    vt[((size_t)b<<20) + (size_t)(d0+ty+8*r)*1024 + n0+tx] = t[tx][ty+8*r];
}

__global__ void bias_concat_kernel(const float* __restrict__ bq,
                                   const float* __restrict__ bkv,
                                   float* __restrict__ dst){
  int i = blockIdx.x*256 + threadIdx.x;
  if (i < 3072) dst[i] = (i < 1024) ? bq[i] : bkv[i-1024];
}

// ---------------- layernorm (row = 1024 floats) -----------------------------
__global__ __launch_bounds__(256) void ln_kernel(const float* __restrict__ x,
                                                 unsigned short* __restrict__ xn){
  const int C = 1024;
  size_t row = blockIdx.x;
  float4 v = reinterpret_cast<const float4*>(x + row*C)[threadIdx.x];
  float s = v.x+v.y+v.z+v.w;
  float q = v.x*v.x+v.y*v.y+v.z*v.z+v.w*v.w;
  #pragma unroll
  for (int off=32; off; off>>=1){ s += __shfl_xor(s,off); q += __shfl_xor(q,off); }
  __shared__ float sm[8];
  int wv = threadIdx.x>>6, ln = threadIdx.x&63;
  if (ln==0){ sm[wv]=s; sm[4+wv]=q; }
  __syncthreads();
  float S = sm[0]+sm[1]+sm[2]+sm[3];
  float Q = sm[4]+sm[5]+sm[6]+sm[7];
  float mu  = S*(1.0f/1024.0f);
  float var = Q*(1.0f/1024.0f) - mu*mu;
  float inv = rsqrtf(var + 1e-6f);
  ushort4 o;
  o.x = f32_to_bf16((v.x-mu)*inv);
  o.y = f32_to_bf16((v.y-mu)*inv);
  o.z = f32_to_bf16((v.z-mu)*inv);
  o.w = f32_to_bf16((v.w-mu)*inv);
  reinterpret_cast<ushort4*>(xn + row*C)[threadIdx.x] = o;
}

// ---------------- bf16 MFMA GEMM: C = A[M,K] * BT[N,K]^T (+epilogue) --------
// EPI 0: bias -> bf16 out ; EPI 1: bias+residual -> f32 out ; EPI 2: bias+gelu -> bf16 out
template<int EPI>
__global__ __launch_bounds__(256) void gemm_kernel(
    const unsigned short* __restrict__ A,
    const unsigned short* __restrict__ BT,
    const float* __restrict__ bias,
    const float* __restrict__ resid,
    void* __restrict__ Cout,
    int M, int N, int K)
{
  __shared__ __align__(16) unsigned short lA[2][128*32];
  __shared__ __align__(16) unsigned short lB[2][128*32];
  int tid = threadIdx.x, wave = tid>>6, lane = tid&63;
  int m0 = blockIdx.y*128, n0 = blockIdx.x*128;
  int ln = lane&15, g = lane>>4;

  int srow = wave*16 + (lane>>2);
  int scol = (lane&3)*8;
  const unsigned short* gA0 = A  + (size_t)(m0+srow)*K    + scol;
  const unsigned short* gA1 = A  + (size_t)(m0+64+srow)*K + scol;
  const unsigned short* gB0 = BT + (size_t)(n0+srow)*K    + scol;
  const unsigned short* gB1 = BT + (size_t)(n0+64+srow)*K + scol;
  int lof0 = wave*512;
  int lof1 = 64*32 + wave*512;

  f32x4 acc[4][4] = {};
  int wm = wave>>1, wn = wave&1;

  int nt = K/32;
  gload16(gA0, &lA[0][lof0]);
  gload16(gA1, &lA[0][lof1]);
  gload16(gB0, &lB[0][lof0]);
  gload16(gB1, &lB[0][lof1]);
  __syncthreads();
  int cur = 0;
  for (int t=0; t<nt; ++t){
    if (t+1 < nt){
      int ko = (t+1)*32;
      gload16(gA0+ko, &lA[cur^1][lof0]);
      gload16(gA1+ko, &lA[cur^1][lof1]);
      gload16(gB0+ko, &lB[cur^1][lof0]);
      gload16(gB1+ko, &lB[cur^1][lof1]);
    }
    bf16x8 a[4], b[4];
    const unsigned short* pA = &lA[cur][(wm*64+ln)*32 + g*8];
    const unsigned short* pB = &lB[cur][(wn*64+ln)*32 + g*8];
    #pragma unroll
    for (int i=0;i<4;i++){
      a[i] = *(const bf16x8*)(pA + i*16*32);
      b[i] = *(const bf16x8*)(pB + i*16*32);
    }
    #pragma unroll
    for (int mi=0;mi<4;mi++)
      #pragma unroll
      for (int ni=0;ni<4;ni++)
        acc[mi][ni] = MFMA16(a[mi], b[ni], acc[mi][ni]);
    __syncthreads();
    cur ^= 1;
  }

  #pragma unroll
  for (int mi=0;mi<4;mi++){
    int r0 = m0 + wm*64 + mi*16 + g*4;
    #pragma unroll
    for (int ni=0;ni<4;ni++){
      int c = n0 + wn*64 + ni*16 + ln;
      float bs = bias[c];
      f32x4 cc = acc[mi][ni];
      #pragma unroll
      for (int i=0;i<4;i++){
        int r = r0 + i;
        float v = cc[i] + bs;
        if (EPI == 1){
          v += resid[(size_t)r*N + c];
          ((float*)Cout)[(size_t)r*N + c] = v;
        } else if (EPI == 2){
          ((unsigned short*)Cout)[(size_t)r*N + c] = f32_to_bf16(gelu_tanh(v));
        } else {
          ((unsigned short*)Cout)[(size_t)r*N + c] = f32_to_bf16(v);
        }
      }
    }
  }
}

// ---------------- fused attention (barrier-free) ----------------------------
// qkv [4096][3072] bf16 ; vt [b][1024 d][1024 n] bf16 ; biasb [1024][1024] f32
// grid (64 bh, 16 qt) x 256. Each wave owns 16 q-rows. Fixed-max softmax.
__global__ __launch_bounds__(256) void attn_kernel(
    const unsigned short* __restrict__ qkv,
    const unsigned short* __restrict__ vt,
    const float* __restrict__ biasb,
    unsigned short* __restrict__ o)
{
  const int N = 1024, NK = 3072;
  const float SCL = 0.18033688011112042f;   // 0.125 * log2(e)
  __shared__ __align__(16) unsigned short plds[4][16][72];  // [wave][q][j] pad->2-way
  int bh = blockIdx.x, qt = blockIdx.y;
  int b = bh>>4, h = bh&15;
  int tid = threadIdx.x, wave = tid>>6, lane = tid&63;
  int ln = lane&15, g = lane>>4;
  size_t base = (size_t)b*N;
  int q_local = qt*64 + wave*16;

  const unsigned short* qptr = qkv + (base + q_local + ln)*NK + h*64;
  bf16x8 aq0 = *(const bf16x8*)(qptr + g*8);
  bf16x8 aq1 = *(const bf16x8*)(qptr + 32 + g*8);

  f32x4 oacc[4] = {};
  float lsum[4] = {0.f,0.f,0.f,0.f};
  const unsigned short* vbase = vt + ((size_t)b<<20) + (size_t)(h*64)*N;

  for (int j0=0; j0<N; j0+=64){
    // ---- QK^T : S[16q][64j] per wave
    f32x4 s[4] = {};
    #pragma unroll
    for (int jj=0;jj<4;jj++){
      const unsigned short* kp = qkv + (base + j0 + jj*16 + ln)*NK + 1024 + h*64;
      bf16x8 k0 = *(const bf16x8*)(kp + g*8);
      bf16x8 k1 = *(const bf16x8*)(kp + 32 + g*8);
      s[jj] = MFMA16(aq0, k0, s[jj]);
      s[jj] = MFMA16(aq1, k1, s[jj]);
    }
    // ---- fixed-max softmax numerator + P^T into per-wave LDS
    #pragma unroll
    for (int i=0;i<4;i++){
      int qr = q_local + 4*g + i;
      const float* bp = biasb + (size_t)qr*N + j0 + ln;
      #pragma unroll
      for (int jj=0;jj<4;jj++){
        float e = exp2f(fmaf(s[jj][i], SCL, bp[jj*16]));
        lsum[i] += e;
        plds[wave][4*g+i][jj*16+ln] = f32_to_bf16(e);
      }
    }
    asm volatile("s_waitcnt lgkmcnt(0)" ::: "memory");
    __builtin_amdgcn_sched_barrier(0);
    bf16x8 p0 = *(const bf16x8*)&plds[wave][ln][g*8];
    bf16x8 p1 = *(const bf16x8*)&plds[wave][ln][32 + g*8];
    // ---- PV from global VT (L2-resident, row-major)
    #pragma unroll
    for (int nd=0;nd<4;nd++){
      const unsigned short* vp = vbase + (size_t)(nd*16+ln)*N + j0;
      bf16x8 v0 = *(const bf16x8*)(vp + g*8);
      bf16x8 v1 = *(const bf16x8*)(vp + 32 + g*8);
      oacc[nd] = MFMA16(p0, v0, oacc[nd]);
      oacc[nd] = MFMA16(p1, v1, oacc[nd]);
    }
  }

  #pragma unroll
  for (int i=0;i<4;i++){
    float l = lsum[i];
    l += __shfl_xor(l,1); l += __shfl_xor(l,2);
    l += __shfl_xor(l,4); l += __shfl_xor(l,8);
    lsum[i] = 1.0f/l;
  }
  #pragma unroll
  for (int nd=0;nd<4;nd++){
    #pragma unroll
    for (int i=0;i<4;i++){
      int qr = q_local + 4*g + i;
      o[(base+qr)*1024 + h*64 + nd*16 + ln] = f32_to_bf16(oacc[nd][i]*lsum[i]);
    }
  }
}

// ---------------- host ------------------------------------------------------
extern "C" void kernel_launch(void* const* d_in, const int* in_sizes, int n_in,
                              void* d_out, int out_size, void* d_ws, size_t ws_size,
                              hipStream_t stream)
{
  (void)in_sizes; (void)n_in; (void)out_size; (void)ws_size;
  const float* x   = (const float*)d_in[0];
  const void*  mask= d_in[1];
  const float* wq  = (const float*)d_in[2];
  const float* bq  = (const float*)d_in[3];
  const float* wkv = (const float*)d_in[4];
  const float* bkv = (const float*)d_in[5];
  const float* wo  = (const float*)d_in[6];
  const float* bo  = (const float*)d_in[7];
  const float* w1  = (const float*)d_in[8];
  const float* b1  = (const float*)d_in[9];
  const float* w2  = (const float*)d_in[10];
  const float* b2  = (const float*)d_in[11];
  float* out = (float*)d_out;

  char* ws = (char*)d_ws;
  size_t off = 0;
  auto alloc = [&](size_t bytes){ size_t o = off; off += (bytes + 255) & ~(size_t)255; return o; };
  unsigned short* WqkvT = (unsigned short*)(ws + alloc(3072u*1024u*2));  // 6MB
  unsigned short* WoT   = (unsigned short*)(ws + alloc(1024u*1024u*2));  // 2MB
  unsigned short* W1T   = (unsigned short*)(ws + alloc(4096u*1024u*2));  // 8MB
  unsigned short* W2T   = (unsigned short*)(ws + alloc(1024u*4096u*2));  // 8MB
  float*          BIASQ = (float*)(ws + alloc(3072u*4));
  int*            FLAG  = (int*)(ws + alloc(256));
  float*          MBIAS = (float*)(ws + alloc(1024u*1024u*4));           // 4MB
  unsigned short* XN    = (unsigned short*)(ws + alloc(4096u*1024u*2));  // 8MB
  float*          X1    = (float*)(ws + alloc(4096u*1024u*4));           // 16MB
  unsigned short* QKV   = (unsigned short*)(ws + alloc(4096u*4096u*2));  // 32MB (qkv 24MB; VT aliases last 8MB; h later)
  unsigned short* VT    = QKV + (size_t)4096u*3072u;                     // [4][1024][1024]

  // prep
  transpose_cvt_kernel<<<dim3(32,32),  256, 0, stream>>>(wq,  WqkvT,               1024, 1024);
  transpose_cvt_kernel<<<dim3(64,32),  256, 0, stream>>>(wkv, WqkvT + 1024u*1024u, 1024, 2048);
  transpose_cvt_kernel<<<dim3(32,32),  256, 0, stream>>>(wo,  WoT,                 1024, 1024);
  transpose_cvt_kernel<<<dim3(128,32), 256, 0, stream>>>(w1,  W1T,                 1024, 4096);
  transpose_cvt_kernel<<<dim3(32,128), 256, 0, stream>>>(w2,  W2T,                 4096, 1024);
  bias_concat_kernel<<<12, 256, 0, stream>>>(bq, bkv, BIASQ);
  detect_mask_kernel<<<1, 256, 0, stream>>>((const unsigned*)mask, FLAG);
  mask_bias_kernel<<<4096, 256, 0, stream>>>(mask, FLAG, MBIAS);

  // block
  ln_kernel<<<4096, 256, 0, stream>>>(x, XN);
  gemm_kernel<0><<<dim3(24,32), 256, 0, stream>>>(XN, WqkvT, BIASQ, nullptr, QKV, 4096, 3072, 1024);
  vtrans_kernel<<<dim3(32,32,4), 256, 0, stream>>>(QKV, VT);
  attn_kernel<<<dim3(64,16), 256, 0, stream>>>(QKV, VT, MBIAS, XN);
  gemm_kernel<1><<<dim3(8,32), 256, 0, stream>>>(XN, WoT, bo, x, X1, 4096, 1024, 1024);
  ln_kernel<<<4096, 256, 0, stream>>>(X1, XN);
  gemm_kernel<2><<<dim3(32,32), 256, 0, stream>>>(XN, W1T, b1, nullptr, QKV, 4096, 4096, 1024);
  gemm_kernel<1><<<dim3(8,32), 256, 0, stream>>>(QKV, W2T, b2, X1, out, 4096, 1024, 4096);
}

// Round 3
// 378.338 us; speedup vs baseline: 1.1404x; 1.0103x over previous
//
#include <hip/hip_runtime.h>
#include <hip/hip_bf16.h>

typedef short bf16x8 __attribute__((ext_vector_type(8)));
typedef float f32x4 __attribute__((ext_vector_type(4)));

#define MFMA16(a,b,c) __builtin_amdgcn_mfma_f32_16x16x32_bf16((a),(b),(c),0,0,0)

__device__ inline unsigned short f32_to_bf16(float f){
  union { float f; unsigned u; } v; v.f = f;
  unsigned u = v.u;
  u += 0x7FFFu + ((u >> 16) & 1u);
  return (unsigned short)(u >> 16);
}

__device__ inline float gelu_tanh(float x){
  float x3 = x*x*x;
  float t = tanhf(0.7978845608028654f*(x + 0.044715f*x3));
  return 0.5f*x*(1.0f+t);
}

__device__ inline void gload16(const void* g, void* l){
  __builtin_amdgcn_global_load_lds(
      (const __attribute__((address_space(1))) void*)g,
      (__attribute__((address_space(3))) void*)l, 16, 0, 0);
}

// ---------------- mask dtype detection -------------------------------------
__global__ void detect_mask_kernel(const unsigned* __restrict__ m, int* __restrict__ flag){
  __shared__ int s;
  if (threadIdx.x == 0) s = 0;
  __syncthreads();
  unsigned w = m[threadIdx.x];
  if (w > 1u) atomicOr(&s, 1);
  __syncthreads();
  if (threadIdx.x == 0) *flag = s;   // 1 => byte/bool storage, 0 => int32
}

// mask -> additive bias, pre-scaled by log2(e), fixed-max shift M=16 folded in.
__global__ __launch_bounds__(256) void mask_bias_kernel(
    const void* __restrict__ mask, const int* __restrict__ flag, float* __restrict__ bias){
  int i = blockIdx.x*256 + threadIdx.x;
  bool a = (*flag) ? (((const unsigned char*)mask)[i] != 0)
                   : (((const int*)mask)[i] != 0);
  bias[i] = a ? -23.083120654223414f : -1e30f;
}

// ---------------- weight convert + transpose -------------------------------
__global__ __launch_bounds__(256) void transpose_cvt_kernel(
    const float* __restrict__ W, unsigned short* __restrict__ WT, int K, int N){
  __shared__ float tile[32][33];
  int n0 = blockIdx.x*32, k0 = blockIdx.y*32;
  int tx = threadIdx.x & 31, ty = threadIdx.x >> 5;
  #pragma unroll
  for (int r=0;r<4;r++)
    tile[ty+8*r][tx] = W[(size_t)(k0+ty+8*r)*N + n0+tx];
  __syncthreads();
  #pragma unroll
  for (int r=0;r<4;r++)
    WT[(size_t)(n0+ty+8*r)*K + k0+tx] = f32_to_bf16(tile[tx][ty+8*r]);
}

// V slice of qkv [4096][3072] -> VT [b][1024 d][1024 n] bf16
__global__ __launch_bounds__(256) void vtrans_kernel(
    const unsigned short* __restrict__ qkv, unsigned short* __restrict__ vt){
  __shared__ unsigned short t[32][33];
  int b = blockIdx.z;
  int n0 = blockIdx.x*32, d0 = blockIdx.y*32;
  int tx = threadIdx.x & 31, ty = threadIdx.x >> 5;
  #pragma unroll
  for (int r=0;r<4;r++)
    t[ty+8*r][tx] = qkv[(size_t)(b*1024 + n0+ty+8*r)*3072 + 2048 + d0+tx];
  __syncthreads();
  #pragma unroll
  for (int r=0;r<4;r++)
    vt[((size_t)b<<20) + (size_t)(d0+ty+8*r)*1024 + n0+tx] = t[tx][ty+8*r];
}

__global__ void bias_concat_kernel(const float* __restrict__ bq,
                                   const float* __restrict__ bkv,
                                   float* __restrict__ dst){
  int i = blockIdx.x*256 + threadIdx.x;
  if (i < 3072) dst[i] = (i < 1024) ? bq[i] : bkv[i-1024];
}

// ---------------- layernorm (row = 1024 floats) -----------------------------
__global__ __launch_bounds__(256) void ln_kernel(const float* __restrict__ x,
                                                 unsigned short* __restrict__ xn){
  const int C = 1024;
  size_t row = blockIdx.x;
  float4 v = reinterpret_cast<const float4*>(x + row*C)[threadIdx.x];
  float s = v.x+v.y+v.z+v.w;
  float q = v.x*v.x+v.y*v.y+v.z*v.z+v.w*v.w;
  #pragma unroll
  for (int off=32; off; off>>=1){ s += __shfl_xor(s,off); q += __shfl_xor(q,off); }
  __shared__ float sm[8];
  int wv = threadIdx.x>>6, ln = threadIdx.x&63;
  if (ln==0){ sm[wv]=s; sm[4+wv]=q; }
  __syncthreads();
  float S = sm[0]+sm[1]+sm[2]+sm[3];
  float Q = sm[4]+sm[5]+sm[6]+sm[7];
  float mu  = S*(1.0f/1024.0f);
  float var = Q*(1.0f/1024.0f) - mu*mu;
  float inv = rsqrtf(var + 1e-6f);
  ushort4 o;
  o.x = f32_to_bf16((v.x-mu)*inv);
  o.y = f32_to_bf16((v.y-mu)*inv);
  o.z = f32_to_bf16((v.z-mu)*inv);
  o.w = f32_to_bf16((v.w-mu)*inv);
  reinterpret_cast<ushort4*>(xn + row*C)[threadIdx.x] = o;
}

// ---------------- 2-phase 128x128 GEMM (kept for N=1024 outputs) ------------
// EPI 0: bias->bf16 ; EPI 1: bias+residual->f32 ; EPI 2: bias+gelu->bf16
template<int EPI>
__global__ __launch_bounds__(256) void gemm_kernel(
    const unsigned short* __restrict__ A,
    const unsigned short* __restrict__ BT,
    const float* __restrict__ bias,
    const float* __restrict__ resid,
    void* __restrict__ Cout,
    int M, int N, int K)
{
  __shared__ __align__(16) unsigned short lA[2][128*32];
  __shared__ __align__(16) unsigned short lB[2][128*32];
  int tid = threadIdx.x, wave = tid>>6, lane = tid&63;
  int m0 = blockIdx.y*128, n0 = blockIdx.x*128;
  int ln = lane&15, g = lane>>4;

  int srow = wave*16 + (lane>>2);
  int scol = (lane&3)*8;
  const unsigned short* gA0 = A  + (size_t)(m0+srow)*K    + scol;
  const unsigned short* gA1 = A  + (size_t)(m0+64+srow)*K + scol;
  const unsigned short* gB0 = BT + (size_t)(n0+srow)*K    + scol;
  const unsigned short* gB1 = BT + (size_t)(n0+64+srow)*K + scol;
  int lof0 = wave*512;
  int lof1 = 64*32 + wave*512;

  f32x4 acc[4][4] = {};
  int wm = wave>>1, wn = wave&1;

  int nt = K/32;
  gload16(gA0, &lA[0][lof0]);
  gload16(gA1, &lA[0][lof1]);
  gload16(gB0, &lB[0][lof0]);
  gload16(gB1, &lB[0][lof1]);
  __syncthreads();
  int cur = 0;
  for (int t=0; t<nt; ++t){
    if (t+1 < nt){
      int ko = (t+1)*32;
      gload16(gA0+ko, &lA[cur^1][lof0]);
      gload16(gA1+ko, &lA[cur^1][lof1]);
      gload16(gB0+ko, &lB[cur^1][lof0]);
      gload16(gB1+ko, &lB[cur^1][lof1]);
    }
    bf16x8 a[4], b[4];
    const unsigned short* pA = &lA[cur][(wm*64+ln)*32 + g*8];
    const unsigned short* pB = &lB[cur][(wn*64+ln)*32 + g*8];
    #pragma unroll
    for (int i=0;i<4;i++){
      a[i] = *(const bf16x8*)(pA + i*16*32);
      b[i] = *(const bf16x8*)(pB + i*16*32);
    }
    #pragma unroll
    for (int mi=0;mi<4;mi++)
      #pragma unroll
      for (int ni=0;ni<4;ni++)
        acc[mi][ni] = MFMA16(a[mi], b[ni], acc[mi][ni]);
    __syncthreads();
    cur ^= 1;
  }

  #pragma unroll
  for (int mi=0;mi<4;mi++){
    int r0 = m0 + wm*64 + mi*16 + g*4;
    #pragma unroll
    for (int ni=0;ni<4;ni++){
      int c = n0 + wn*64 + ni*16 + ln;
      float bs = bias[c];
      f32x4 cc = acc[mi][ni];
      #pragma unroll
      for (int i=0;i<4;i++){
        int r = r0 + i;
        float v = cc[i] + bs;
        if (EPI == 1){
          v += resid[(size_t)r*N + c];
          ((float*)Cout)[(size_t)r*N + c] = v;
        } else if (EPI == 2){
          ((unsigned short*)Cout)[(size_t)r*N + c] = f32_to_bf16(gelu_tanh(v));
        } else {
          ((unsigned short*)Cout)[(size_t)r*N + c] = f32_to_bf16(v);
        }
      }
    }
  }
}

// ---------------- 8-phase 256x256 GEMM (T2+T3+T4+T5) ------------------------
// BM=BN=256, BK=64 (2 K-halves of 32). 512 thr / 8 waves (2x4), wave out 128x64.
// LDS 128KiB dynamic: A[2buf][2kh][256][32] @0, B same @65536.
// Swizzle: col_byte ^= (row&3)<<4, applied on stage source AND ds_read.
// Stage schedule at tile t: ph1->(t+1,Bkh1) ph2->(t+2,Akh0) ph3->(t+2,Bkh0)
// ph4->(t+2,Akh1); vmcnt(6) at ph4 keeps 3 half-tiles in flight.
template<int EPI>
__global__ __launch_bounds__(512) void gemm8_kernel(
    const unsigned short* __restrict__ A,
    const unsigned short* __restrict__ BT,
    const float* __restrict__ bias,
    void* __restrict__ Cout,
    int M, int N, int K)
{
  extern __shared__ __align__(16) char smem[];
  const int tid = threadIdx.x, wave = tid>>6, lane = tid&63;
  const int ln = lane&15, g = lane>>4;
  const int wm = wave>>2, wn = wave&3;
  const int m0 = blockIdx.y*256, n0 = blockIdx.x*256;
  const int NT = K>>6;
  const int axor = (g*16) ^ ((ln&3)<<4);   // byte offset within 64B row

  auto STAGE = [&](int kt, int h){  // h: 0=Akh0 1=Bkh0 2=Akh1 3=Bkh1
    const bool isB = h&1; const int kh = h>>1;
    const unsigned short* src = isB ? BT : A;
    const int base0 = isB ? n0 : m0;
    char* region = smem + (isB?65536:0) + (kt&1)*32768 + kh*16384;
    #pragma unroll
    for (int r=0;r<2;r++){
      int idx = r*512 + tid;
      int row = idx>>2;
      int col = kt*64 + kh*32 + ((((idx&3)*16) ^ ((row&3)<<4))>>1);
      gload16(src + (size_t)(base0+row)*K + col,
              region + (r*512 + wave*64)*16);
    }
  };

  // prologue: tile0 all 4 halves + tile1 first 3 halves
  STAGE(0,0); STAGE(0,1); STAGE(0,2); STAGE(0,3);
  STAGE(1,0); STAGE(1,1); STAGE(1,2);
  asm volatile("s_waitcnt vmcnt(6)" ::: "memory");
  __builtin_amdgcn_s_barrier();
  __builtin_amdgcn_sched_barrier(0);

  f32x4 acc[8][4] = {};
  bf16x8 a[8], b[2];

  for (int t=0; t<NT; ++t){
    const int cur = t&1;
    char* Ac0 = smem + cur*32768;
    char* Ac1 = Ac0 + 16384;
    char* Bc0 = smem + 65536 + cur*32768;
    char* Bc1 = Bc0 + 16384;
    // ---- ph1: A kh0 + B kh0 nh0
    #pragma unroll
    for (int mi=0;mi<8;mi++)
      a[mi] = *(const bf16x8*)(Ac0 + (wm*128+mi*16+ln)*64 + axor);
    b[0] = *(const bf16x8*)(Bc0 + (wn*64+ 0+ln)*64 + axor);
    b[1] = *(const bf16x8*)(Bc0 + (wn*64+16+ln)*64 + axor);
    if (t+1 < NT) STAGE(t+1,3);
    __builtin_amdgcn_s_barrier();
    __builtin_amdgcn_s_setprio(1);
    #pragma unroll
    for (int mi=0;mi<8;mi++){
      acc[mi][0] = MFMA16(a[mi], b[0], acc[mi][0]);
      acc[mi][1] = MFMA16(a[mi], b[1], acc[mi][1]);
    }
    __builtin_amdgcn_s_setprio(0);
    __builtin_amdgcn_s_barrier();
    // ---- ph2: B kh0 nh1
    b[0] = *(const bf16x8*)(Bc0 + (wn*64+32+ln)*64 + axor);
    b[1] = *(const bf16x8*)(Bc0 + (wn*64+48+ln)*64 + axor);
    if (t+2 < NT) STAGE(t+2,0);
    __builtin_amdgcn_s_barrier();
    __builtin_amdgcn_s_setprio(1);
    #pragma unroll
    for (int mi=0;mi<8;mi++){
      acc[mi][2] = MFMA16(a[mi], b[0], acc[mi][2]);
      acc[mi][3] = MFMA16(a[mi], b[1], acc[mi][3]);
    }
    __builtin_amdgcn_s_setprio(0);
    __builtin_amdgcn_s_barrier();
    // ---- ph3: A kh1 + B kh1 nh0
    #pragma unroll
    for (int mi=0;mi<8;mi++)
      a[mi] = *(const bf16x8*)(Ac1 + (wm*128+mi*16+ln)*64 + axor);
    b[0] = *(const bf16x8*)(Bc1 + (wn*64+ 0+ln)*64 + axor);
    b[1] = *(const bf16x8*)(Bc1 + (wn*64+16+ln)*64 + axor);
    if (t+2 < NT) STAGE(t+2,1);
    __builtin_amdgcn_s_barrier();
    __builtin_amdgcn_s_setprio(1);
    #pragma unroll
    for (int mi=0;mi<8;mi++){
      acc[mi][0] = MFMA16(a[mi], b[0], acc[mi][0]);
      acc[mi][1] = MFMA16(a[mi], b[1], acc[mi][1]);
    }
    __builtin_amdgcn_s_setprio(0);
    __builtin_amdgcn_s_barrier();
    // ---- ph4: B kh1 nh1
    b[0] = *(const bf16x8*)(Bc1 + (wn*64+32+ln)*64 + axor);
    b[1] = *(const bf16x8*)(Bc1 + (wn*64+48+ln)*64 + axor);
    if (t+2 < NT) STAGE(t+2,2);
    __builtin_amdgcn_s_barrier();
    __builtin_amdgcn_s_setprio(1);
    #pragma unroll
    for (int mi=0;mi<8;mi++){
      acc[mi][2] = MFMA16(a[mi], b[0], acc[mi][2]);
      acc[mi][3] = MFMA16(a[mi], b[1], acc[mi][3]);
    }
    __builtin_amdgcn_s_setprio(0);
    if (t+2 < NT) asm volatile("s_waitcnt vmcnt(6)" ::: "memory");
    else          asm volatile("s_waitcnt vmcnt(0)" ::: "memory");
    __builtin_amdgcn_s_barrier();
    __builtin_amdgcn_sched_barrier(0);
  }

  // ---- epilogue
  #pragma unroll
  for (int mi=0;mi<8;mi++){
    int r0 = m0 + wm*128 + mi*16 + g*4;
    #pragma unroll
    for (int nj=0;nj<4;nj++){
      int c = n0 + wn*64 + nj*16 + ln;
      float bs = bias[c];
      f32x4 cc = acc[mi][nj];
      #pragma unroll
      for (int i=0;i<4;i++){
        int r = r0 + i;
        float v = cc[i] + bs;
        if (EPI == 2){
          ((unsigned short*)Cout)[(size_t)r*N + c] = f32_to_bf16(gelu_tanh(v));
        } else {
          ((unsigned short*)Cout)[(size_t)r*N + c] = f32_to_bf16(v);
        }
      }
    }
  }
}

// ---------------- fused attention ------------------------------------------
// qkv [4096][3072] bf16 ; vt [b][1024 d][1024 n] bf16 ; biasb [1024][1024] f32
__global__ __launch_bounds__(256,4) void attn_kernel(
    const unsigned short* __restrict__ qkv,
    const unsigned short* __restrict__ vt,
    const float* __restrict__ biasb,
    unsigned short* __restrict__ o)
{
  const int N = 1024, NK = 3072;
  const float SCL = 0.18033688011112042f;   // 0.125 * log2(e)
  __shared__ __align__(16) unsigned short plds[4][16][72];
  int bh = blockIdx.x, qt = blockIdx.y;
  int b = bh>>4, h = bh&15;
  int tid = threadIdx.x, wave = tid>>6, lane = tid&63;
  int ln = lane&15, g = lane>>4;
  size_t base = (size_t)b*N;
  int q_local = qt*64 + wave*16;

  const unsigned short* qptr = qkv + (base + q_local + ln)*NK + h*64;
  bf16x8 aq0 = *(const bf16x8*)(qptr + g*8);
  bf16x8 aq1 = *(const bf16x8*)(qptr + 32 + g*8);

  f32x4 oacc[4] = {};
  float lsum[4] = {0.f,0.f,0.f,0.f};
  const unsigned short* vbase = vt + ((size_t)b<<20) + (size_t)(h*64)*N;

  auto loadK = [&](int j0, bf16x8* kk){
    #pragma unroll
    for (int jj=0;jj<4;jj++){
      const unsigned short* kp = qkv + (base + j0 + jj*16 + ln)*NK + 1024 + h*64;
      kk[2*jj]   = *(const bf16x8*)(kp + g*8);
      kk[2*jj+1] = *(const bf16x8*)(kp + 32 + g*8);
    }
  };

  bf16x8 kf[8], kn[8];
  loadK(0, kf);

  for (int j0=0; j0<N; j0+=64){
    // ---- QK^T : S[16q][64j] per wave
    f32x4 s[4] = {};
    #pragma unroll
    for (int jj=0;jj<4;jj++){
      s[jj] = MFMA16(aq0, kf[2*jj],   s[jj]);
      s[jj] = MFMA16(aq1, kf[2*jj+1], s[jj]);
    }
    // prefetch next tile's K (hides L2 latency under softmax+PV)
    if (j0+64 < N) loadK(j0+64, kn);
    // ---- fixed-max softmax numerator + P^T into per-wave LDS
    #pragma unroll
    for (int i=0;i<4;i++){
      int qr = q_local + 4*g + i;
      const float* bp = biasb + (size_t)qr*N + j0 + ln;
      #pragma unroll
      for (int jj=0;jj<4;jj++){
        float e = exp2f(fmaf(s[jj][i], SCL, bp[jj*16]));
        lsum[i] += e;
        plds[wave][4*g+i][jj*16+ln] = f32_to_bf16(e);
      }
    }
    asm volatile("s_waitcnt lgkmcnt(0)" ::: "memory");
    bf16x8 p0 = *(const bf16x8*)&plds[wave][ln][g*8];
    bf16x8 p1 = *(const bf16x8*)&plds[wave][ln][32 + g*8];
    // ---- PV from global VT (L2-resident)
    #pragma unroll
    for (int nd=0;nd<4;nd++){
      const unsigned short* vp = vbase + (size_t)(nd*16+ln)*N + j0;
      bf16x8 v0 = *(const bf16x8*)(vp + g*8);
      bf16x8 v1 = *(const bf16x8*)(vp + 32 + g*8);
      oacc[nd] = MFMA16(p0, v0, oacc[nd]);
      oacc[nd] = MFMA16(p1, v1, oacc[nd]);
    }
    #pragma unroll
    for (int e=0;e<8;e++) kf[e] = kn[e];
  }

  #pragma unroll
  for (int i=0;i<4;i++){
    float l = lsum[i];
    l += __shfl_xor(l,1); l += __shfl_xor(l,2);
    l += __shfl_xor(l,4); l += __shfl_xor(l,8);
    lsum[i] = 1.0f/l;
  }
  #pragma unroll
  for (int nd=0;nd<4;nd++){
    #pragma unroll
    for (int i=0;i<4;i++){
      int qr = q_local + 4*g + i;
      o[(base+qr)*1024 + h*64 + nd*16 + ln] = f32_to_bf16(oacc[nd][i]*lsum[i]);
    }
  }
}

// ---------------- host ------------------------------------------------------
extern "C" void kernel_launch(void* const* d_in, const int* in_sizes, int n_in,
                              void* d_out, int out_size, void* d_ws, size_t ws_size,
                              hipStream_t stream)
{
  (void)in_sizes; (void)n_in; (void)out_size; (void)ws_size;
  const float* x   = (const float*)d_in[0];
  const void*  mask= d_in[1];
  const float* wq  = (const float*)d_in[2];
  const float* bq  = (const float*)d_in[3];
  const float* wkv = (const float*)d_in[4];
  const float* bkv = (const float*)d_in[5];
  const float* wo  = (const float*)d_in[6];
  const float* bo  = (const float*)d_in[7];
  const float* w1  = (const float*)d_in[8];
  const float* b1  = (const float*)d_in[9];
  const float* w2  = (const float*)d_in[10];
  const float* b2  = (const float*)d_in[11];
  float* out = (float*)d_out;

  char* ws = (char*)d_ws;
  size_t off = 0;
  auto alloc = [&](size_t bytes){ size_t o = off; off += (bytes + 255) & ~(size_t)255; return o; };
  unsigned short* WqkvT = (unsigned short*)(ws + alloc(3072u*1024u*2));
  unsigned short* WoT   = (unsigned short*)(ws + alloc(1024u*1024u*2));
  unsigned short* W1T   = (unsigned short*)(ws + alloc(4096u*1024u*2));
  unsigned short* W2T   = (unsigned short*)(ws + alloc(1024u*4096u*2));
  float*          BIASQ = (float*)(ws + alloc(3072u*4));
  int*            FLAG  = (int*)(ws + alloc(256));
  float*          MBIAS = (float*)(ws + alloc(1024u*1024u*4));
  unsigned short* XN    = (unsigned short*)(ws + alloc(4096u*1024u*2));
  float*          X1    = (float*)(ws + alloc(4096u*1024u*4));
  unsigned short* QKV   = (unsigned short*)(ws + alloc(4096u*4096u*2));
  unsigned short* VT    = QKV + (size_t)4096u*3072u;

  // allow 128KiB dynamic LDS for the 8-phase GEMM
  hipFuncSetAttribute(reinterpret_cast<const void*>(&gemm8_kernel<0>),
                      hipFuncAttributeMaxDynamicSharedMemorySize, 131072);
  hipFuncSetAttribute(reinterpret_cast<const void*>(&gemm8_kernel<2>),
                      hipFuncAttributeMaxDynamicSharedMemorySize, 131072);

  // prep
  transpose_cvt_kernel<<<dim3(32,32),  256, 0, stream>>>(wq,  WqkvT,               1024, 1024);
  transpose_cvt_kernel<<<dim3(64,32),  256, 0, stream>>>(wkv, WqkvT + 1024u*1024u, 1024, 2048);
  transpose_cvt_kernel<<<dim3(32,32),  256, 0, stream>>>(wo,  WoT,                 1024, 1024);
  transpose_cvt_kernel<<<dim3(128,32), 256, 0, stream>>>(w1,  W1T,                 1024, 4096);
  transpose_cvt_kernel<<<dim3(32,128), 256, 0, stream>>>(w2,  W2T,                 4096, 1024);
  bias_concat_kernel<<<12, 256, 0, stream>>>(bq, bkv, BIASQ);
  detect_mask_kernel<<<1, 256, 0, stream>>>((const unsigned*)mask, FLAG);
  mask_bias_kernel<<<4096, 256, 0, stream>>>(mask, FLAG, MBIAS);

  // block
  ln_kernel<<<4096, 256, 0, stream>>>(x, XN);
  gemm8_kernel<0><<<dim3(12,16), 512, 131072, stream>>>(XN, WqkvT, BIASQ, QKV, 4096, 3072, 1024);
  vtrans_kernel<<<dim3(32,32,4), 256, 0, stream>>>(QKV, VT);
  attn_kernel<<<dim3(64,16), 256, 0, stream>>>(QKV, VT, MBIAS, XN);
  gemm_kernel<1><<<dim3(8,32), 256, 0, stream>>>(XN, WoT, bo, x, X1, 4096, 1024, 1024);
  ln_kernel<<<4096, 256, 0, stream>>>(X1, XN);
  gemm8_kernel<2><<<dim3(16,16), 512, 131072, stream>>>(XN, W1T, b1, QKV, 4096, 4096, 1024);
  gemm_kernel<1><<<dim3(8,32), 256, 0, stream>>>(QKV, W2T, b2, X1, out, 4096, 1024, 4096);
}